// Round 4
// baseline (3568.496 us; speedup 1.0000x reference)
//
#include <hip/hip_runtime.h>
#include <math.h>

// Problem constants
#define T_C 8
#define K_C 64
#define NB_C 16
#define D_C 512
#define H_C 512
#define B_C 512
#define NSTEP 32          // only first 32 EM steps feed the loss (ys[3:32:4])
constexpr float DT_F   = 1.0f / 64.0f;
constexpr float SQDT_F = 0.125f;

// ---------------------------------------------------------------------------
// SDE kernel v5: 256 blocks (4 per k, disjoint 128-col weight slices), 512 thr.
// v4 lesson: __syncthreads() drains vmcnt(0) -> weight-prefetch pipeline was
// drained 64x/step. v5 stages weights via global_load_lds DMA into a 3-deep
// ring of 16-row chunks per net, with RAW s_barrier + counted vmcnt(2): loads
// for chunks c+1/c+2 stay in flight across barriers (T3+T4 pattern). One
// barrier per chunk, zero drains inside a layer. LDS dest is linear
// (wave-uniform base + lane*16 == row-major [16][128]); per-output d-order
// stays sequential 0..511 -> bit-exact vs reference.
// ---------------------------------------------------------------------------
#define QSYNC()                                                              \
    do {                                                                     \
        __syncthreads();                                                     \
        if (tid == 0) {                                                      \
            target += 4;                                                     \
            __hip_atomic_fetch_add(&cnt[k], 1u, __ATOMIC_RELEASE,            \
                                   __HIP_MEMORY_SCOPE_AGENT);                \
            unsigned _sp = 0;                                                \
            while (__hip_atomic_load(&cnt[k], __ATOMIC_ACQUIRE,              \
                                     __HIP_MEMORY_SCOPE_AGENT) < target) {   \
                __builtin_amdgcn_s_sleep(2);                                 \
                if (++_sp > 100000000u) break; /* bailout: never hang */     \
            }                                                                \
        }                                                                    \
        __syncthreads();                                                     \
    } while (0)

// counted waitcnt + scheduling fence (rule #18)
#define WAITV2() do { asm volatile("s_waitcnt vmcnt(2)" ::: "memory"); \
                      __builtin_amdgcn_sched_barrier(0); } while (0)
#define WAITV0() do { asm volatile("s_waitcnt vmcnt(0)" ::: "memory"); \
                      __builtin_amdgcn_sched_barrier(0); } while (0)
#define RAWBAR() do { __builtin_amdgcn_s_barrier(); \
                      __builtin_amdgcn_sched_barrier(0); } while (0)

__global__ __launch_bounds__(512, 1) void sde_kernel(
    const float* __restrict__ init_mu, const float* __restrict__ init_noise,
    const float* __restrict__ Wf1, const float* __restrict__ bf1,
    const float* __restrict__ Wf2, const float* __restrict__ bf2,
    const float* __restrict__ Wg1, const float* __restrict__ bg1,
    const float* __restrict__ Wg2, const float* __restrict__ bg2,
    const float* __restrict__ dW, float* __restrict__ path,
    float* __restrict__ hbuf, float* __restrict__ ybuf,
    unsigned* __restrict__ cnt)
{
    // Quartet-on-one-XCD swizzle (perf only; sync is agent-scope atomics).
    const int b    = blockIdx.x;
    const int xcd  = b & 7;
    const int slot = b >> 3;              // 0..31
    const int k    = xcd * 8 + (slot >> 2);
    const int c_   = slot & 3;
    const int js   = c_ * 128;            // this block's column slice

    const int tid  = threadIdx.x;
    const int net  = tid >> 8;            // 0 = drift(f) net, 1 = diffusion(g)
    const int tt   = tid & 255;
    const int wid  = tt >> 6;             // wave id within net: 0..3
    const int lane = tid & 63;
    const int r0   = wid * 4;             // row quad
    const int cg   = tt & 63;
    const int jj   = cg * 2;              // slice-local col
    const int col  = js + jj;             // global col

    __shared__ __align__(16) float y_s[512][16];   // [d][row], broadcast reads
    __shared__ __align__(16) float h_s[512][16];
    __shared__ __align__(16) float g_s[512][16];
    __shared__ __align__(16) float wst[2][3][2048]; // per-net 3-ring of 16x128
    __shared__ float tmp[16][128];                  // diffusion handoff g->f

    for (int idx = tid; idx < 8192; idx += 512) {
        int d = idx >> 4, r = idx & 15;
        y_s[d][r] = init_mu[k * 512 + d]
                  + 0.05f * init_noise[((size_t)(k * 16 + r)) * 512 + d];
    }

    const size_t koff = (size_t)k * 262144;
    const float* W1 = (net ? Wg1 : Wf1) + koff;
    const float* W2 = (net ? Wg2 : Wf2) + koff;
    const float2 b1 = *(const float2*)((net ? bg1 : bf1) + k * 512 + col);
    const float2 b2 = *(const float2*)((net ? bg2 : bf2) + k * 512 + col);

    float* hb = hbuf + (size_t)net * 524288 + (size_t)k * 8192; // [512][16]
    float* yb = ybuf + (size_t)k * 8192;                        // [512][16]

    float* wstn = &wst[net][0][0];
    // DMA one 16-row chunk of a weight slice into ring buffer `buf`.
    // Wave covers rows (wid*2+r)*2 + (lane>>5), cols (lane&31)*4 within slice.
    // LDS dest = wave-uniform base + lane*16 (linear == row-major [16][128]).
    #define ISSUE_CHUNK(W, chunk, buf)                                       \
        {                                                                    \
            _Pragma("unroll")                                                \
            for (int r = 0; r < 2; ++r) {                                    \
                const float* gp = (W) + (size_t)((chunk) * 16 +              \
                                  (wid * 2 + r) * 2 + (lane >> 5)) * 512     \
                                  + js + (lane & 31) * 4;                    \
                float* lp = wstn + (buf) * 2048 + (wid * 2 + r) * 256;       \
                __builtin_amdgcn_global_load_lds(gp, lp, 16, 0, 0);          \
            }                                                                \
        }

    unsigned target = 0;
    __syncthreads();

    for (int s = 0; s < NSTEP; ++s) {
        // Hoist dW loads (f net only); they are older than all chunk DMAs,
        // so the first counted wait forces them complete.
        float2 dw0, dw1, dw2, dw3;
        if (!net) {
            const size_t dwb = (((size_t)s * 64 + k) * 16 + r0) * 512 + col;
            dw0 = *(const float2*)(dW + dwb);
            dw1 = *(const float2*)(dW + dwb + 512);
            dw2 = *(const float2*)(dW + dwb + 1024);
            dw3 = *(const float2*)(dW + dwb + 1536);
        }

        // ===== layer 1: a[r][col] = sum_d y[r][d] * W1[d][col] =====
        float a00 = 0.f, a01 = 0.f, a10 = 0.f, a11 = 0.f;
        float a20 = 0.f, a21 = 0.f, a30 = 0.f, a31 = 0.f;
        ISSUE_CHUNK(W1, 0, 0);
        ISSUE_CHUNK(W1, 1, 1);
        for (int c = 0; c < 31; ++c) {
            WAITV2();              // my chunk-c parts landed (c+1 may fly)
            RAWBAR();              // everyone's chunk c landed; c-1 buf free
            if (c + 2 < 32) ISSUE_CHUNK(W1, c + 2, (c + 2) % 3);
            const float* wb = wstn + (c % 3) * 2048;
            const int d0 = c * 16;
            #pragma unroll 8
            for (int dl = 0; dl < 16; ++dl) {
                float2 w  = *(const float2*)&wb[dl * 128 + jj];
                float4 yv = *(const float4*)&y_s[d0 + dl][r0];
                a00 += yv.x * w.x; a01 += yv.x * w.y;
                a10 += yv.y * w.x; a11 += yv.y * w.y;
                a20 += yv.z * w.x; a21 += yv.z * w.y;
                a30 += yv.w * w.x; a31 += yv.w * w.y;
            }
        }
        {   // peeled last chunk (c = 31, buffer 31 % 3 = 1)
            WAITV0();
            RAWBAR();
            const float* wb = wstn + 1 * 2048;
            #pragma unroll 8
            for (int dl = 0; dl < 16; ++dl) {
                float2 w  = *(const float2*)&wb[dl * 128 + jj];
                float4 yv = *(const float4*)&y_s[496 + dl][r0];
                a00 += yv.x * w.x; a01 += yv.x * w.y;
                a10 += yv.y * w.x; a11 += yv.y * w.y;
                a20 += yv.z * w.x; a21 += yv.z * w.y;
                a30 += yv.w * w.x; a31 += yv.w * w.y;
            }
        }
        {
            float4 hv0 = make_float4(tanhf(a00 + b1.x), tanhf(a10 + b1.x),
                                     tanhf(a20 + b1.x), tanhf(a30 + b1.x));
            float4 hv1 = make_float4(tanhf(a01 + b1.y), tanhf(a11 + b1.y),
                                     tanhf(a21 + b1.y), tanhf(a31 + b1.y));
            *(float4*)(hb + (size_t)col * 16 + r0)       = hv0;
            *(float4*)(hb + (size_t)(col + 1) * 16 + r0) = hv1;
        }

        QSYNC();   // h/g slices from all 4 siblings now visible

        {   // gather full h, g into LDS
            const float4* hsrc = (const float4*)(hbuf + (size_t)k * 8192);
            const float4* gsrc = (const float4*)(hbuf + 524288 + (size_t)k * 8192);
            float4* hdst = (float4*)&h_s[0][0];
            float4* gdst = (float4*)&g_s[0][0];
            for (int i = tid; i < 2048; i += 512) { hdst[i] = hsrc[i]; gdst[i] = gsrc[i]; }
        }
        __syncthreads();

        // ===== layer 2: c[r][col] = sum_hh h[r][hh] * W2[hh][col] =====
        const float* hsrc2 = net ? &g_s[0][0] : &h_s[0][0];
        float c00 = 0.f, c01 = 0.f, c10 = 0.f, c11 = 0.f;
        float c20 = 0.f, c21 = 0.f, c30 = 0.f, c31 = 0.f;
        ISSUE_CHUNK(W2, 0, 0);
        ISSUE_CHUNK(W2, 1, 1);
        for (int c2 = 0; c2 < 31; ++c2) {
            WAITV2();
            RAWBAR();
            if (c2 + 2 < 32) ISSUE_CHUNK(W2, c2 + 2, (c2 + 2) % 3);
            const float* wb = wstn + (c2 % 3) * 2048;
            const int h0 = c2 * 16;
            #pragma unroll 8
            for (int dl = 0; dl < 16; ++dl) {
                float2 w  = *(const float2*)&wb[dl * 128 + jj];
                float4 hv = *(const float4*)(hsrc2 + (size_t)(h0 + dl) * 16 + r0);
                c00 += hv.x * w.x; c01 += hv.x * w.y;
                c10 += hv.y * w.x; c11 += hv.y * w.y;
                c20 += hv.z * w.x; c21 += hv.z * w.y;
                c30 += hv.w * w.x; c31 += hv.w * w.y;
            }
        }
        {   // peeled last chunk (c2 = 31, buffer 1)
            WAITV0();
            RAWBAR();
            const float* wb = wstn + 1 * 2048;
            #pragma unroll 8
            for (int dl = 0; dl < 16; ++dl) {
                float2 w  = *(const float2*)&wb[dl * 128 + jj];
                float4 hv = *(const float4*)(hsrc2 + (size_t)(496 + dl) * 16 + r0);
                c00 += hv.x * w.x; c01 += hv.x * w.y;
                c10 += hv.y * w.x; c11 += hv.y * w.y;
                c20 += hv.z * w.x; c21 += hv.z * w.y;
                c30 += hv.w * w.x; c31 += hv.w * w.y;
            }
        }

        if (net) {  // diffusion: 0.1*sigmoid(. + bg2) -> tmp
            tmp[r0 + 0][jj]     = 0.1f / (1.f + expf(-(c00 + b2.x)));
            tmp[r0 + 0][jj + 1] = 0.1f / (1.f + expf(-(c01 + b2.y)));
            tmp[r0 + 1][jj]     = 0.1f / (1.f + expf(-(c10 + b2.x)));
            tmp[r0 + 1][jj + 1] = 0.1f / (1.f + expf(-(c11 + b2.y)));
            tmp[r0 + 2][jj]     = 0.1f / (1.f + expf(-(c20 + b2.x)));
            tmp[r0 + 2][jj + 1] = 0.1f / (1.f + expf(-(c21 + b2.y)));
            tmp[r0 + 3][jj]     = 0.1f / (1.f + expf(-(c30 + b2.x)));
            tmp[r0 + 3][jj + 1] = 0.1f / (1.f + expf(-(c31 + b2.y)));
        }
        __syncthreads();
        if (!net) { // drift net finalizes: y' = y + drift*dt + diff*(sqdt*dw)
            float o00 = y_s[col][r0+0]   + (c00 + b2.x) * DT_F + tmp[r0+0][jj]   * (SQDT_F * dw0.x);
            float o01 = y_s[col+1][r0+0] + (c01 + b2.y) * DT_F + tmp[r0+0][jj+1] * (SQDT_F * dw0.y);
            float o10 = y_s[col][r0+1]   + (c10 + b2.x) * DT_F + tmp[r0+1][jj]   * (SQDT_F * dw1.x);
            float o11 = y_s[col+1][r0+1] + (c11 + b2.y) * DT_F + tmp[r0+1][jj+1] * (SQDT_F * dw1.y);
            float o20 = y_s[col][r0+2]   + (c20 + b2.x) * DT_F + tmp[r0+2][jj]   * (SQDT_F * dw2.x);
            float o21 = y_s[col+1][r0+2] + (c21 + b2.y) * DT_F + tmp[r0+2][jj+1] * (SQDT_F * dw2.y);
            float o30 = y_s[col][r0+3]   + (c30 + b2.x) * DT_F + tmp[r0+3][jj]   * (SQDT_F * dw3.x);
            float o31 = y_s[col+1][r0+3] + (c31 + b2.y) * DT_F + tmp[r0+3][jj+1] * (SQDT_F * dw3.y);
            *(float4*)(yb + (size_t)col * 16 + r0)       = make_float4(o00, o10, o20, o30);
            *(float4*)(yb + (size_t)(col + 1) * 16 + r0) = make_float4(o01, o11, o21, o31);
            if ((s & 3) == 3) {
                const int t = s >> 2;
                const size_t pb = (((size_t)t * 64 + k) * 16 + r0) * 512 + col;
                *(float2*)(path + pb)        = make_float2(o00, o01);
                *(float2*)(path + pb + 512)  = make_float2(o10, o11);
                *(float2*)(path + pb + 1024) = make_float2(o20, o21);
                *(float2*)(path + pb + 1536) = make_float2(o30, o31);
            }
        }

        QSYNC();   // y slices from all 4 siblings now visible

        if (s != NSTEP - 1) {
            const float4* ysrc = (const float4*)yb;
            float4* ydst = (float4*)&y_s[0][0];
            for (int i = tid; i < 2048; i += 512) ydst[i] = ysrc[i];
            __syncthreads();
        }
    }
    #undef ISSUE_CHUNK
}

// ---------------------------------------------------------------------------
// z row norms: znorm[t*512+j] = sum_d z[t][j][d]^2. One wave per row.
// ---------------------------------------------------------------------------
__global__ __launch_bounds__(256) void znorm_kernel(const float* __restrict__ z,
                                                    float* __restrict__ znorm)
{
    const int row  = blockIdx.x * 4 + (threadIdx.x >> 6);   // 0..4095
    const int lane = threadIdx.x & 63;
    const float* zr = z + (size_t)row * 512;
    float s = 0.f;
    for (int d = lane; d < 512; d += 64) { float v = zr[d]; s += v * v; }
    #pragma unroll
    for (int off = 32; off > 0; off >>= 1) s += __shfl_down(s, off);
    if (lane == 0) znorm[row] = s;
}

// ---------------------------------------------------------------------------
// G[t][i][j] = sum_d zhat[t][i][d] * z[t][j][d]   (A@B^T, both k-contiguous)
// tile 64x64, BK=64, 256 threads, 4x4 per thread.
// ---------------------------------------------------------------------------
__global__ __launch_bounds__(256) void gemm_kernel(const float* __restrict__ path,
                                                   const float* __restrict__ z,
                                                   float* __restrict__ G)
{
    const int jt = blockIdx.x;   // 0..7
    const int it = blockIdx.y;   // 0..15
    const int t  = blockIdx.z;   // 0..7
    const float* A  = path + (size_t)t * 1024 * 512 + (size_t)it * 64 * 512;
    const float* Bz = z    + (size_t)t * 512 * 512 + (size_t)jt * 64 * 512;
    float* Gp = G + (size_t)t * 1024 * 512 + (size_t)it * 64 * 512 + jt * 64;

    __shared__ float As[64][65];
    __shared__ float Bs[64][65];
    const int tid = threadIdx.x;
    const int tx = tid & 15, ty = tid >> 4;
    const int lr = tid >> 2;
    const int lc = (tid & 3) * 16;

    float acc[4][4] = {};
    for (int kt = 0; kt < 512; kt += 64) {
        #pragma unroll
        for (int u = 0; u < 4; ++u) {
            float4 av = *(const float4*)(A  + (size_t)lr * 512 + kt + lc + u * 4);
            float4 bv = *(const float4*)(Bz + (size_t)lr * 512 + kt + lc + u * 4);
            As[lr][lc + u * 4 + 0] = av.x; As[lr][lc + u * 4 + 1] = av.y;
            As[lr][lc + u * 4 + 2] = av.z; As[lr][lc + u * 4 + 3] = av.w;
            Bs[lr][lc + u * 4 + 0] = bv.x; Bs[lr][lc + u * 4 + 1] = bv.y;
            Bs[lr][lc + u * 4 + 2] = bv.z; Bs[lr][lc + u * 4 + 3] = bv.w;
        }
        __syncthreads();
        #pragma unroll 8
        for (int kk = 0; kk < 64; ++kk) {
            float a0 = As[ty][kk], a1 = As[ty + 16][kk], a2 = As[ty + 32][kk], a3 = As[ty + 48][kk];
            float b0 = Bs[tx][kk], b1 = Bs[tx + 16][kk], b2 = Bs[tx + 32][kk], b3 = Bs[tx + 48][kk];
            acc[0][0] += a0 * b0; acc[0][1] += a0 * b1; acc[0][2] += a0 * b2; acc[0][3] += a0 * b3;
            acc[1][0] += a1 * b0; acc[1][1] += a1 * b1; acc[1][2] += a1 * b2; acc[1][3] += a1 * b3;
            acc[2][0] += a2 * b0; acc[2][1] += a2 * b1; acc[2][2] += a2 * b2; acc[2][3] += a2 * b3;
            acc[3][0] += a3 * b0; acc[3][1] += a3 * b1; acc[3][2] += a3 * b2; acc[3][3] += a3 * b3;
        }
        __syncthreads();
    }
    #pragma unroll
    for (int mi = 0; mi < 4; ++mi)
        #pragma unroll
        for (int mj = 0; mj < 4; ++mj)
            Gp[(size_t)(ty + mi * 16) * 512 + tx + mj * 16] = acc[mi][mj];
}

// ---------------------------------------------------------------------------
// Per (t,i): argmax_j [2G - ||z_j||^2 + (y_j==cls ? 0 : -1e6)], then
// mse partial = sum_d (zhat[i,d] - z[pair,d])^2.  One block per (t,i).
// ---------------------------------------------------------------------------
__global__ __launch_bounds__(256) void pair_mse_kernel(
    const float* __restrict__ G, const float* __restrict__ znorm,
    const int* __restrict__ all_y, const float* __restrict__ path,
    const float* __restrict__ all_z, float* __restrict__ mse_part)
{
    const int t = blockIdx.x >> 10;
    const int i = blockIdx.x & 1023;
    const int cls = i >> 4;              // path_y[i] = i / NB
    const int tid = threadIdx.x;
    const float* Gr = G + ((size_t)t * 1024 + i) * 512;

    float best = -3.4e38f;
    int bestj = 0x7fffffff;
    for (int j = tid; j < 512; j += 256) {
        float sc = 2.f * Gr[j] - znorm[t * 512 + j];
        if (all_y[t * 512 + j] != cls) sc -= 1e6f;
        if (sc > best || (sc == best && j < bestj)) { best = sc; bestj = j; }
    }
    #pragma unroll
    for (int off = 32; off > 0; off >>= 1) {
        float ob = __shfl_down(best, off);
        int   oj = __shfl_down(bestj, off);
        if (ob > best || (ob == best && oj < bestj)) { best = ob; bestj = oj; }
    }
    __shared__ float sb[4];
    __shared__ int   sj[4];
    if ((tid & 63) == 0) { sb[tid >> 6] = best; sj[tid >> 6] = bestj; }
    __syncthreads();
    if (tid == 0) {
        for (int w = 1; w < 4; ++w)
            if (sb[w] > sb[0] || (sb[w] == sb[0] && sj[w] < sj[0])) { sb[0] = sb[w]; sj[0] = sj[w]; }
    }
    __syncthreads();
    const int pair = sj[0];

    const float* zh = path  + ((size_t)t * 1024 + i) * 512;
    const float* zr = all_z + ((size_t)t * 512 + pair) * 512;
    float ssum = 0.f;
    for (int d = tid; d < 512; d += 256) {
        float df = zh[d] - zr[d];
        ssum += df * df;
    }
    #pragma unroll
    for (int off = 32; off > 0; off >>= 1) ssum += __shfl_down(ssum, off);
    __shared__ float sred[4];
    if ((tid & 63) == 0) sred[tid >> 6] = ssum;
    __syncthreads();
    if (tid == 0) mse_part[blockIdx.x] = sred[0] + sred[1] + sred[2] + sred[3];
}

// ---------------------------------------------------------------------------
// CE: per (t, j-tile of 64). allc_j = sum_i e, pos_j = sum_{i: i/16==y_j} e,
// e = (sim<10 ? exp(sim) : 1).  ce_val[t*512+j] = log(allc+eps)-log(pos+eps)
// ---------------------------------------------------------------------------
__global__ __launch_bounds__(256) void ce_kernel(const float* __restrict__ G,
                                                 const int* __restrict__ all_y,
                                                 float* __restrict__ ce_val)
{
    const int t  = blockIdx.x >> 3;
    const int j0 = (blockIdx.x & 7) * 64;
    const int tid = threadIdx.x;
    const int jj = tid & 63, ig = tid >> 6;
    const int j = j0 + jj;
    const int cls = all_y[t * 512 + j];
    const float* Gt = G + (size_t)t * 1024 * 512;

    float alc = 0.f, pos = 0.f;
    for (int i = ig; i < 1024; i += 4) {
        float s = Gt[(size_t)i * 512 + j];
        float e = (s < 10.f) ? expf(s) : 1.f;
        alc += e;
        if ((i >> 4) == cls) pos += e;
    }
    __shared__ float as_[4][64];
    __shared__ float ps_[4][64];
    as_[ig][jj] = alc; ps_[ig][jj] = pos;
    __syncthreads();
    if (tid < 64) {
        float a = as_[0][tid] + as_[1][tid] + as_[2][tid] + as_[3][tid];
        float p = ps_[0][tid] + ps_[1][tid] + ps_[2][tid] + ps_[3][tid];
        ce_val[t * 512 + j0 + tid] = logf(a + 1e-7f) - logf(p + 1e-7f);
    }
}

// ---------------------------------------------------------------------------
// Final deterministic reduction: loss = mean_t( ce_t + mse_t )
// ---------------------------------------------------------------------------
__global__ __launch_bounds__(256) void final_kernel(const float* __restrict__ mse_part,
                                                    const float* __restrict__ ce_val,
                                                    float* __restrict__ out)
{
    const int tid = threadIdx.x;
    float ms = 0.f, cs = 0.f;
    for (int i = tid; i < 8192; i += 256) ms += mse_part[i];
    for (int i = tid; i < 4096; i += 256) cs += ce_val[i];
    #pragma unroll
    for (int off = 32; off > 0; off >>= 1) {
        ms += __shfl_down(ms, off);
        cs += __shfl_down(cs, off);
    }
    __shared__ float mred[4], cred[4];
    if ((tid & 63) == 0) { mred[tid >> 6] = ms; cred[tid >> 6] = cs; }
    __syncthreads();
    if (tid == 0) {
        float M = mred[0] + mred[1] + mred[2] + mred[3];
        float C = cred[0] + cred[1] + cred[2] + cred[3];
        out[0] = C / (8.f * 512.f) + M / (8.f * 1024.f * 512.f);
    }
}

extern "C" void kernel_launch(void* const* d_in, const int* in_sizes, int n_in,
                              void* d_out, int out_size, void* d_ws, size_t ws_size,
                              hipStream_t stream) {
    const float* all_z      = (const float*)d_in[0];
    const int*   all_y      = (const int*)d_in[1];
    const float* init_mu    = (const float*)d_in[2];
    const float* Wf1        = (const float*)d_in[3];
    const float* bf1        = (const float*)d_in[4];
    const float* Wf2        = (const float*)d_in[5];
    const float* bf2        = (const float*)d_in[6];
    const float* Wg1        = (const float*)d_in[7];
    const float* bg1        = (const float*)d_in[8];
    const float* Wg2        = (const float*)d_in[9];
    const float* bg2        = (const float*)d_in[10];
    const float* init_noise = (const float*)d_in[11];
    const float* dW         = (const float*)d_in[12];
    float* out = (float*)d_out;

    float* ws       = (float*)d_ws;
    float* path     = ws;                             // 8*64*16*512 = 4194304 floats
    float* G        = ws + (size_t)4194304;           // 8*1024*512  = 4194304 floats
    float* znorm    = G  + (size_t)4194304;           // 4096
    float* mse_part = znorm + 4096;                   // 8192
    float* ce_val   = mse_part + 8192;                // 4096

    // SDE exchange buffers live inside the G region (G is only written later
    // by gemm_kernel, after sde_kernel completes on the same stream).
    float* hbuf = G;                                  // 64*512*16 *2 nets = 1048576
    float* ybuf = G + (size_t)1048576;                // 64*512*16 = 524288
    unsigned* cnt = (unsigned*)(G + (size_t)4194304 - 64);  // 64 quartet counters

    hipMemsetAsync(cnt, 0, 64 * sizeof(unsigned), stream);
    sde_kernel<<<256, 512, 0, stream>>>(init_mu, init_noise, Wf1, bf1, Wf2, bf2,
                                        Wg1, bg1, Wg2, bg2, dW, path,
                                        hbuf, ybuf, cnt);
    znorm_kernel<<<1024, 256, 0, stream>>>(all_z, znorm);
    gemm_kernel<<<dim3(8, 16, 8), 256, 0, stream>>>(path, all_z, G);
    pair_mse_kernel<<<8192, 256, 0, stream>>>(G, znorm, all_y, path, all_z, mse_part);
    ce_kernel<<<64, 256, 0, stream>>>(G, all_y, ce_val);
    final_kernel<<<1, 256, 0, stream>>>(mse_part, ce_val, out);
}

// Round 6
// 2533.997 us; speedup vs baseline: 1.4082x; 1.4082x over previous
//
#include <hip/hip_runtime.h>
#include <math.h>

// Problem constants
#define T_C 8
#define K_C 64
#define NB_C 16
#define D_C 512
#define H_C 512
#define B_C 512
#define NSTEP 32          // only first 32 EM steps feed the loss (ys[3:32:4])
constexpr float DT_F   = 1.0f / 64.0f;
constexpr float SQDT_F = 0.125f;

// ---------------------------------------------------------------------------
// SDE kernel v7: ROW-split quartet (v6 structure) + race-free ring handoff.
// v6 raced: layer-boundary prologue ISSUE wrote ring slot off+2 right after
// L1CHUNK(62) read it (no fence between the ds_reads and the DMA issue ->
// compiler may interleave; DMA write can land before reads are serviced).
// v7: prologue chunk 0 -> slot off+1 (safe: last read one full fenced
// iteration earlier); prologue chunk 1 -> slot off+2 issued AFTER the next
// __syncthreads() (implicit lgkmcnt(0) proves all chunk-62 reads done;
// builtins cannot hoist across the barrier). vmcnt accounting re-derived for
// both nets at all boundaries; correct whether or not the barrier drains vm.
// Per-output d-order stays sequential 0..511 -> bit-exact vs reference.
// ---------------------------------------------------------------------------

#define WAITV4() do { asm volatile("s_waitcnt vmcnt(4)" ::: "memory"); \
                      __builtin_amdgcn_sched_barrier(0); } while (0)
#define WAITV0() do { asm volatile("s_waitcnt vmcnt(0)" ::: "memory"); \
                      __builtin_amdgcn_sched_barrier(0); } while (0)
#define WRAP3(x) ((x) >= 3 ? (x) - 3 : (x))

__global__ __launch_bounds__(512, 1) void sde_kernel(
    const float* __restrict__ init_mu, const float* __restrict__ init_noise,
    const float* __restrict__ Wf1, const float* __restrict__ bf1,
    const float* __restrict__ Wf2, const float* __restrict__ bf2,
    const float* __restrict__ Wg1, const float* __restrict__ bg1,
    const float* __restrict__ Wg2, const float* __restrict__ bg2,
    const float* __restrict__ dW, float* __restrict__ path)
{
    // Quartet-on-one-XCD swizzle: siblings (same k, 4 row-groups) land on one
    // XCD so their identical weight streams dedup in its L2.
    const int b    = blockIdx.x;
    const int xcd  = b & 7;
    const int slot = b >> 3;              // 0..31
    const int k    = xcd * 8 + (slot >> 2);
    const int q    = slot & 3;            // row-group within k
    const int nb0  = q * 4;               // this block's 4 nb-rows

    const int tid  = threadIdx.x;
    const int net  = tid >> 8;            // 0 = drift(f), 1 = diffusion(g)
    const int tt   = tid & 255;
    const int w    = tt >> 6;             // wave within net: 0..3
    const int gw   = tid >> 6;            // global wave 0..7 (private ring id)
    const int lane = tid & 63;
    const int wcol0 = w * 128;            // this wave's 128-col slice
    const int col  = wcol0 + 2 * lane;    // this thread's 2 cols

    __shared__ __align__(16) float y_s[512][4];    // [d][row] broadcast
    __shared__ __align__(16) float h_s[512][4];
    __shared__ __align__(16) float g_s[512][4];
    __shared__ __align__(16) float tmp[512][4];    // diffusion handoff g->f
    __shared__ __align__(16) float wst[8][3][1024];// per-wave ring: 8rx128c

    for (int idx = tid; idx < 2048; idx += 512) {
        int d = idx >> 2, r = idx & 3;
        y_s[d][r] = init_mu[k * 512 + d]
                  + 0.05f * init_noise[((size_t)(k * 16 + nb0 + r)) * 512 + d];
    }

    const size_t koff = (size_t)k * 262144;
    const float* W1 = (net ? Wg1 : Wf1) + koff;
    const float* W2 = (net ? Wg2 : Wf2) + koff;
    const float2 b1 = *(const float2*)((net ? bg1 : bf1) + k * 512 + col);
    const float2 b2 = *(const float2*)((net ? bg2 : bf2) + k * 512 + col);

    // DMA one 8-row x 128-col chunk of W into this wave's private ring slot.
    // 4 insts x (64 lanes x 16B) = 4KB. LDS dest = uniform base + lane*16B
    // (hardware adds lane*size); global src is per-lane.
    #define ISSUE(W_, ch, sl)                                                \
        do {                                                                 \
            const float* gpc = (W_) + (size_t)(ch) * 4096 + wcol0            \
                             + (lane >> 5) * 512 + (lane & 31) * 4;          \
            float* lpc = &wst[gw][sl][0];                                    \
            __builtin_amdgcn_global_load_lds(gpc,        lpc,       16,0,0); \
            __builtin_amdgcn_global_load_lds(gpc + 1024, lpc + 256, 16,0,0); \
            __builtin_amdgcn_global_load_lds(gpc + 2048, lpc + 512, 16,0,0); \
            __builtin_amdgcn_global_load_lds(gpc + 3072, lpc + 768, 16,0,0); \
        } while (0)

    #define L1CHUNK(c, sl)                                                   \
        {                                                                    \
            const float* wb = &wst[gw][sl][0];                               \
            _Pragma("unroll")                                                \
            for (int dl = 0; dl < 8; ++dl) {                                 \
                float2 wv = *(const float2*)&wb[dl * 128 + (lane << 1)];     \
                float4 yv = *(const float4*)&y_s[(c) * 8 + dl][0];           \
                a00 += yv.x * wv.x; a01 += yv.x * wv.y;                      \
                a10 += yv.y * wv.x; a11 += yv.y * wv.y;                      \
                a20 += yv.z * wv.x; a21 += yv.z * wv.y;                      \
                a30 += yv.w * wv.x; a31 += yv.w * wv.y;                      \
            }                                                                \
        }

    #define L2CHUNK(c, sl)                                                   \
        {                                                                    \
            const float* wb = &wst[gw][sl][0];                               \
            _Pragma("unroll")                                                \
            for (int dl = 0; dl < 8; ++dl) {                                 \
                float2 wv = *(const float2*)&wb[dl * 128 + (lane << 1)];     \
                float4 hv = *(const float4*)(hsp + ((c) * 8 + dl) * 4);      \
                c00 += hv.x * wv.x; c01 += hv.x * wv.y;                      \
                c10 += hv.y * wv.x; c11 += hv.y * wv.y;                      \
                c20 += hv.z * wv.x; c21 += hv.z * wv.y;                      \
                c30 += hv.w * wv.x; c31 += hv.w * wv.y;                      \
            }                                                                \
        }

    int off = 0;                 // ring-phase of the current layer
    ISSUE(W1, 0, 0);
    ISSUE(W1, 1, 1);
    __syncthreads();             // y_s ready (also completes prologue DMAs)

    for (int s = 0; s < NSTEP; ++s) {
        // dW for finalize (f net only) — issued early, lands mid-layer1.
        float2 dv0, dv1, dv2, dv3;
        if (!net) {
            const float* dp = dW + (((size_t)s * 64 + k) * 16 + nb0) * 512 + col;
            dv0 = *(const float2*)dp;
            dv1 = *(const float2*)(dp + 512);
            dv2 = *(const float2*)(dp + 1024);
            dv3 = *(const float2*)(dp + 1536);
        }

        // ===== layer 1: a[r][col] = sum_d y[r][d] * W1[d][col] =====
        float a00 = 0.f, a01 = 0.f, a10 = 0.f, a11 = 0.f;
        float a20 = 0.f, a21 = 0.f, a30 = 0.f, a31 = 0.f;
        int csl = off;
        for (int c = 0; c < 62; ++c) {
            WAITV4();                         // my chunk-c parts landed
            int isl = WRAP3(csl + 2);
            ISSUE(W1, c + 2, isl);
            L1CHUNK(c, csl);
            csl = WRAP3(csl + 1);
        }
        WAITV4();
        L1CHUNK(62, csl);
        csl = WRAP3(csl + 1);
        const int noff = WRAP3(off + 1);
        // next-layer chunk 0 -> slot off+1: its last reader was chunk 61,
        // one fully-fenced iteration ago -> safe to overwrite now.
        ISSUE(W2, 0, noff);
        WAITV4();                             // retires chunk 63
        L1CHUNK(63, csl);                     // slot off
        {
            float4 hv0 = make_float4(tanhf(a00 + b1.x), tanhf(a10 + b1.x),
                                     tanhf(a20 + b1.x), tanhf(a30 + b1.x));
            float4 hv1 = make_float4(tanhf(a01 + b1.y), tanhf(a11 + b1.y),
                                     tanhf(a21 + b1.y), tanhf(a31 + b1.y));
            float* hd = net ? &g_s[0][0] : &h_s[0][0];
            *(float4*)(hd + col * 4)       = hv0;
            *(float4*)(hd + (col + 1) * 4) = hv1;
        }
        __syncthreads();    // h_s/g_s visible; lgkmcnt(0) => chunk-62 reads done
        // next-layer chunk 1 -> slot off+2 (chunk 62's slot): safe ONLY after
        // the barrier above (v6's race). Builtins can't hoist across a barrier.
        ISSUE(W2, 1, WRAP3(noff + 1));
        off = noff;

        // ===== layer 2: c[r][col] = sum_hh h[r][hh] * W2[hh][col] =====
        const float* hsp = net ? &g_s[0][0] : &h_s[0][0];
        float c00 = 0.f, c01 = 0.f, c10 = 0.f, c11 = 0.f;
        float c20 = 0.f, c21 = 0.f, c30 = 0.f, c31 = 0.f;
        csl = off;
        for (int c = 0; c < 62; ++c) {
            WAITV4();
            int isl = WRAP3(csl + 2);
            ISSUE(W2, c + 2, isl);
            L2CHUNK(c, csl);
            csl = WRAP3(csl + 1);
        }
        WAITV4();
        L2CHUNK(62, csl);
        csl = WRAP3(csl + 1);
        const int noff2 = WRAP3(off + 1);
        if (s != NSTEP - 1) {
            ISSUE(W1, 0, noff2);              // slot off+1: chunk 61's, safe
            WAITV4();                         // retires chunk 63
        } else {
            WAITV0();
        }
        L2CHUNK(63, csl);                     // slot off

        if (net) {  // diffusion: 0.1*sigmoid(. + bg2) -> tmp
            float4 t0 = make_float4(0.1f / (1.f + expf(-(c00 + b2.x))),
                                    0.1f / (1.f + expf(-(c10 + b2.x))),
                                    0.1f / (1.f + expf(-(c20 + b2.x))),
                                    0.1f / (1.f + expf(-(c30 + b2.x))));
            float4 t1 = make_float4(0.1f / (1.f + expf(-(c01 + b2.y))),
                                    0.1f / (1.f + expf(-(c11 + b2.y))),
                                    0.1f / (1.f + expf(-(c21 + b2.y))),
                                    0.1f / (1.f + expf(-(c31 + b2.y))));
            *(float4*)&tmp[col][0]     = t0;
            *(float4*)&tmp[col + 1][0] = t1;
        }
        __syncthreads();    // tmp visible; lgkmcnt(0) => chunk-62 reads done
        // next step's W1 chunk 1 -> slot off+2 (chunk 62's slot): safe here.
        if (s != NSTEP - 1) ISSUE(W1, 1, WRAP3(noff2 + 1));
        if (!net) { // drift net finalizes: y' = y + drift*dt + diff*(sqdt*dw)
            float4 yo0 = *(const float4*)&y_s[col][0];
            float4 yo1 = *(const float4*)&y_s[col + 1][0];
            float4 tp0 = *(const float4*)&tmp[col][0];
            float4 tp1 = *(const float4*)&tmp[col + 1][0];
            float o00 = yo0.x + (c00 + b2.x) * DT_F + tp0.x * (SQDT_F * dv0.x);
            float o01 = yo1.x + (c01 + b2.y) * DT_F + tp1.x * (SQDT_F * dv0.y);
            float o10 = yo0.y + (c10 + b2.x) * DT_F + tp0.y * (SQDT_F * dv1.x);
            float o11 = yo1.y + (c11 + b2.y) * DT_F + tp1.y * (SQDT_F * dv1.y);
            float o20 = yo0.z + (c20 + b2.x) * DT_F + tp0.z * (SQDT_F * dv2.x);
            float o21 = yo1.z + (c21 + b2.y) * DT_F + tp1.z * (SQDT_F * dv2.y);
            float o30 = yo0.w + (c30 + b2.x) * DT_F + tp0.w * (SQDT_F * dv3.x);
            float o31 = yo1.w + (c31 + b2.y) * DT_F + tp1.w * (SQDT_F * dv3.y);
            *(float4*)&y_s[col][0]     = make_float4(o00, o10, o20, o30);
            *(float4*)&y_s[col + 1][0] = make_float4(o01, o11, o21, o31);
            if ((s & 3) == 3) {
                const int t = s >> 2;
                const size_t pb = (((size_t)t * 64 + k) * 16 + nb0) * 512 + col;
                *(float2*)(path + pb)        = make_float2(o00, o01);
                *(float2*)(path + pb + 512)  = make_float2(o10, o11);
                *(float2*)(path + pb + 1024) = make_float2(o20, o21);
                *(float2*)(path + pb + 1536) = make_float2(o30, o31);
            }
        }
        __syncthreads();    // y_s ready for next step
        off = noff2;
    }
    #undef ISSUE
    #undef L1CHUNK
    #undef L2CHUNK
}

// ---------------------------------------------------------------------------
// z row norms: znorm[t*512+j] = sum_d z[t][j][d]^2. One wave per row.
// ---------------------------------------------------------------------------
__global__ __launch_bounds__(256) void znorm_kernel(const float* __restrict__ z,
                                                    float* __restrict__ znorm)
{
    const int row  = blockIdx.x * 4 + (threadIdx.x >> 6);   // 0..4095
    const int lane = threadIdx.x & 63;
    const float* zr = z + (size_t)row * 512;
    float s = 0.f;
    for (int d = lane; d < 512; d += 64) { float v = zr[d]; s += v * v; }
    #pragma unroll
    for (int off = 32; off > 0; off >>= 1) s += __shfl_down(s, off);
    if (lane == 0) znorm[row] = s;
}

// ---------------------------------------------------------------------------
// G[t][i][j] = sum_d zhat[t][i][d] * z[t][j][d]   (A@B^T, both k-contiguous)
// tile 64x64, BK=64, 256 threads, 4x4 per thread.
// ---------------------------------------------------------------------------
__global__ __launch_bounds__(256) void gemm_kernel(const float* __restrict__ path,
                                                   const float* __restrict__ z,
                                                   float* __restrict__ G)
{
    const int jt = blockIdx.x;   // 0..7
    const int it = blockIdx.y;   // 0..15
    const int t  = blockIdx.z;   // 0..7
    const float* A  = path + (size_t)t * 1024 * 512 + (size_t)it * 64 * 512;
    const float* Bz = z    + (size_t)t * 512 * 512 + (size_t)jt * 64 * 512;
    float* Gp = G + (size_t)t * 1024 * 512 + (size_t)it * 64 * 512 + jt * 64;

    __shared__ float As[64][65];
    __shared__ float Bs[64][65];
    const int tid = threadIdx.x;
    const int tx = tid & 15, ty = tid >> 4;
    const int lr = tid >> 2;
    const int lc = (tid & 3) * 16;

    float acc[4][4] = {};
    for (int kt = 0; kt < 512; kt += 64) {
        #pragma unroll
        for (int u = 0; u < 4; ++u) {
            float4 av = *(const float4*)(A  + (size_t)lr * 512 + kt + lc + u * 4);
            float4 bv = *(const float4*)(Bz + (size_t)lr * 512 + kt + lc + u * 4);
            As[lr][lc + u * 4 + 0] = av.x; As[lr][lc + u * 4 + 1] = av.y;
            As[lr][lc + u * 4 + 2] = av.z; As[lr][lc + u * 4 + 3] = av.w;
            Bs[lr][lc + u * 4 + 0] = bv.x; Bs[lr][lc + u * 4 + 1] = bv.y;
            Bs[lr][lc + u * 4 + 2] = bv.z; Bs[lr][lc + u * 4 + 3] = bv.w;
        }
        __syncthreads();
        #pragma unroll 8
        for (int kk = 0; kk < 64; ++kk) {
            float a0 = As[ty][kk], a1 = As[ty + 16][kk], a2 = As[ty + 32][kk], a3 = As[ty + 48][kk];
            float b0 = Bs[tx][kk], b1 = Bs[tx + 16][kk], b2 = Bs[tx + 32][kk], b3 = Bs[tx + 48][kk];
            acc[0][0] += a0 * b0; acc[0][1] += a0 * b1; acc[0][2] += a0 * b2; acc[0][3] += a0 * b3;
            acc[1][0] += a1 * b0; acc[1][1] += a1 * b1; acc[1][2] += a1 * b2; acc[1][3] += a1 * b3;
            acc[2][0] += a2 * b0; acc[2][1] += a2 * b1; acc[2][2] += a2 * b2; acc[2][3] += a2 * b3;
            acc[3][0] += a3 * b0; acc[3][1] += a3 * b1; acc[3][2] += a3 * b2; acc[3][3] += a3 * b3;
        }
        __syncthreads();
    }
    #pragma unroll
    for (int mi = 0; mi < 4; ++mi)
        #pragma unroll
        for (int mj = 0; mj < 4; ++mj)
            Gp[(size_t)(ty + mi * 16) * 512 + tx + mj * 16] = acc[mi][mj];
}

// ---------------------------------------------------------------------------
// Per (t,i): argmax_j [2G - ||z_j||^2 + (y_j==cls ? 0 : -1e6)], then
// mse partial = sum_d (zhat[i,d] - z[pair,d])^2.  One block per (t,i).
// ---------------------------------------------------------------------------
__global__ __launch_bounds__(256) void pair_mse_kernel(
    const float* __restrict__ G, const float* __restrict__ znorm,
    const int* __restrict__ all_y, const float* __restrict__ path,
    const float* __restrict__ all_z, float* __restrict__ mse_part)
{
    const int t = blockIdx.x >> 10;
    const int i = blockIdx.x & 1023;
    const int cls = i >> 4;              // path_y[i] = i / NB
    const int tid = threadIdx.x;
    const float* Gr = G + ((size_t)t * 1024 + i) * 512;

    float best = -3.4e38f;
    int bestj = 0x7fffffff;
    for (int j = tid; j < 512; j += 256) {
        float sc = 2.f * Gr[j] - znorm[t * 512 + j];
        if (all_y[t * 512 + j] != cls) sc -= 1e6f;
        if (sc > best || (sc == best && j < bestj)) { best = sc; bestj = j; }
    }
    #pragma unroll
    for (int off = 32; off > 0; off >>= 1) {
        float ob = __shfl_down(best, off);
        int   oj = __shfl_down(bestj, off);
        if (ob > best || (ob == best && oj < bestj)) { best = ob; bestj = oj; }
    }
    __shared__ float sb[4];
    __shared__ int   sj[4];
    if ((tid & 63) == 0) { sb[tid >> 6] = best; sj[tid >> 6] = bestj; }
    __syncthreads();
    if (tid == 0) {
        for (int w = 1; w < 4; ++w)
            if (sb[w] > sb[0] || (sb[w] == sb[0] && sj[w] < sj[0])) { sb[0] = sb[w]; sj[0] = sj[w]; }
    }
    __syncthreads();
    const int pair = sj[0];

    const float* zh = path  + ((size_t)t * 1024 + i) * 512;
    const float* zr = all_z + ((size_t)t * 512 + pair) * 512;
    float ssum = 0.f;
    for (int d = tid; d < 512; d += 256) {
        float df = zh[d] - zr[d];
        ssum += df * df;
    }
    #pragma unroll
    for (int off = 32; off > 0; off >>= 1) ssum += __shfl_down(ssum, off);
    __shared__ float sred[4];
    if ((tid & 63) == 0) sred[tid >> 6] = ssum;
    __syncthreads();
    if (tid == 0) mse_part[blockIdx.x] = sred[0] + sred[1] + sred[2] + sred[3];
}

// ---------------------------------------------------------------------------
// CE: per (t, j-tile of 64). allc_j = sum_i e, pos_j = sum_{i: i/16==y_j} e,
// e = (sim<10 ? exp(sim) : 1).  ce_val[t*512+j] = log(allc+eps)-log(pos+eps)
// ---------------------------------------------------------------------------
__global__ __launch_bounds__(256) void ce_kernel(const float* __restrict__ G,
                                                 const int* __restrict__ all_y,
                                                 float* __restrict__ ce_val)
{
    const int t  = blockIdx.x >> 3;
    const int j0 = (blockIdx.x & 7) * 64;
    const int tid = threadIdx.x;
    const int jj = tid & 63, ig = tid >> 6;
    const int j = j0 + jj;
    const int cls = all_y[t * 512 + j];
    const float* Gt = G + (size_t)t * 1024 * 512;

    float alc = 0.f, pos = 0.f;
    for (int i = ig; i < 1024; i += 4) {
        float s = Gt[(size_t)i * 512 + j];
        float e = (s < 10.f) ? expf(s) : 1.f;
        alc += e;
        if ((i >> 4) == cls) pos += e;
    }
    __shared__ float as_[4][64];
    __shared__ float ps_[4][64];
    as_[ig][jj] = alc; ps_[ig][jj] = pos;
    __syncthreads();
    if (tid < 64) {
        float a = as_[0][tid] + as_[1][tid] + as_[2][tid] + as_[3][tid];
        float p = ps_[0][tid] + ps_[1][tid] + ps_[2][tid] + ps_[3][tid];
        ce_val[t * 512 + j0 + tid] = logf(a + 1e-7f) - logf(p + 1e-7f);
    }
}

// ---------------------------------------------------------------------------
// Final deterministic reduction: loss = mean_t( ce_t + mse_t )
// ---------------------------------------------------------------------------
__global__ __launch_bounds__(256) void final_kernel(const float* __restrict__ mse_part,
                                                    const float* __restrict__ ce_val,
                                                    float* __restrict__ out)
{
    const int tid = threadIdx.x;
    float ms = 0.f, cs = 0.f;
    for (int i = tid; i < 8192; i += 256) ms += mse_part[i];
    for (int i = tid; i < 4096; i += 256) cs += ce_val[i];
    #pragma unroll
    for (int off = 32; off > 0; off >>= 1) {
        ms += __shfl_down(ms, off);
        cs += __shfl_down(cs, off);
    }
    __shared__ float mred[4], cred[4];
    if ((tid & 63) == 0) { mred[tid >> 6] = ms; cred[tid >> 6] = cs; }
    __syncthreads();
    if (tid == 0) {
        float M = mred[0] + mred[1] + mred[2] + mred[3];
        float C = cred[0] + cred[1] + cred[2] + cred[3];
        out[0] = C / (8.f * 512.f) + M / (8.f * 1024.f * 512.f);
    }
}

extern "C" void kernel_launch(void* const* d_in, const int* in_sizes, int n_in,
                              void* d_out, int out_size, void* d_ws, size_t ws_size,
                              hipStream_t stream) {
    const float* all_z      = (const float*)d_in[0];
    const int*   all_y      = (const int*)d_in[1];
    const float* init_mu    = (const float*)d_in[2];
    const float* Wf1        = (const float*)d_in[3];
    const float* bf1        = (const float*)d_in[4];
    const float* Wf2        = (const float*)d_in[5];
    const float* bf2        = (const float*)d_in[6];
    const float* Wg1        = (const float*)d_in[7];
    const float* bg1        = (const float*)d_in[8];
    const float* Wg2        = (const float*)d_in[9];
    const float* bg2        = (const float*)d_in[10];
    const float* init_noise = (const float*)d_in[11];
    const float* dW         = (const float*)d_in[12];
    float* out = (float*)d_out;

    float* ws       = (float*)d_ws;
    float* path     = ws;                             // 8*64*16*512 = 4194304 floats
    float* G        = ws + (size_t)4194304;           // 8*1024*512  = 4194304 floats
    float* znorm    = G  + (size_t)4194304;           // 4096
    float* mse_part = znorm + 4096;                   // 8192
    float* ce_val   = mse_part + 8192;                // 4096

    sde_kernel<<<256, 512, 0, stream>>>(init_mu, init_noise, Wf1, bf1, Wf2, bf2,
                                        Wg1, bg1, Wg2, bg2, dW, path);
    znorm_kernel<<<1024, 256, 0, stream>>>(all_z, znorm);
    gemm_kernel<<<dim3(8, 16, 8), 256, 0, stream>>>(path, all_z, G);
    pair_mse_kernel<<<8192, 256, 0, stream>>>(G, znorm, all_y, path, all_z, mse_part);
    ce_kernel<<<64, 256, 0, stream>>>(G, all_y, ce_val);
    final_kernel<<<1, 256, 0, stream>>>(mse_part, ce_val, out);
}